// Round 10
// baseline (226.436 us; speedup 1.0000x reference)
//
#include <hip/hip_runtime.h>
#include <math.h>

#define Bn 8
#define Cn 64
#define Hn 128
#define Wn 128
#define HWn (Hn * Wn)

// weight fragment regions (shorts)
#define WOM_OFF 0
#define WDC_OFF 18432
#define WC_OFF 55296

typedef __attribute__((ext_vector_type(8))) short short8;
typedef __attribute__((ext_vector_type(4))) float floatx4;

__device__ __forceinline__ float bf2f(short s) {
  return __uint_as_float(((unsigned)(unsigned short)s) << 16);
}
__device__ __forceinline__ short f2bf(float f) {
  unsigned u = __float_as_uint(f);
  u += 0x7fff + ((u >> 16) & 1);  // RNE
  return (short)(u >> 16);
}

// ---------------------------------------------------------------------------
// Prep 1: weights -> bf16 MFMA-A-fragment order (unchanged).
// ---------------------------------------------------------------------------
__global__ __launch_bounds__(256) void k_prep_w(
    const float* __restrict__ w_om, const float* __restrict__ w_dc,
    const float* __restrict__ w_c, short* __restrict__ wt) {
  int idx = blockIdx.x * 256 + threadIdx.x;
  if (idx >= 92160) return;
  float v;
  if (idx < WDC_OFF) {  // om region, MT=2 (M=32)
    int e = idx;
    int elem = e & 7, lane = (e >> 3) & 63, mt = (e >> 9) & 1, t = e >> 10;
    int kk = t % 9, cc = t / 9;
    int row = mt * 16 + (lane & 15);
    int cin = cc * 32 + (lane >> 4) * 8 + elem;
    v = (row < 27) ? w_om[(row * 64 + cin) * 9 + kk] : 0.f;
  } else {  // dc / c regions, MT=4 (M=64)
    int e = (idx < WC_OFF) ? idx - WDC_OFF : idx - WC_OFF;
    const float* src = (idx < WC_OFF) ? w_dc : w_c;
    int elem = e & 7, lane = (e >> 3) & 63, mt = (e >> 9) & 3, t = e >> 11;
    int kk = t % 9, cc = t / 9;
    int row = mt * 16 + (lane & 15);
    int cin = cc * 32 + (lane >> 4) * 8 + elem;
    v = src[(row * 64 + cin) * 9 + kk];
  }
  wt[idx] = f2bf(v);
}

// ---------------------------------------------------------------------------
// Prep 2: x fp32 NCHW -> bf16 channels-last xT[b][h][w][64] (unchanged).
// ---------------------------------------------------------------------------
__global__ __launch_bounds__(256) void k_prep_x(const float* __restrict__ x,
                                                short* __restrict__ xT) {
  __shared__ float tile[64][129];
  const int bid = blockIdx.x;
  const int b = bid & 7, h = bid >> 3;
  const int tid = threadIdx.x;
  const float* xb = x + (size_t)b * 64 * HWn + h * Wn;
  for (int i = tid; i < 8192; i += 256) {
    int c = i >> 7, w = i & 127;
    tile[c][w] = xb[c * HWn + w];
  }
  __syncthreads();
  short* dst = xT + ((size_t)(b * Hn + h) * Wn) * 64;
  for (int i = tid; i < 2048; i += 256) {
    int w = i >> 4, c4 = (i & 15) * 4;
    short4 o;
    o.x = f2bf(tile[c4 + 0][w]);
    o.y = f2bf(tile[c4 + 1][w]);
    o.z = f2bf(tile[c4 + 2][w]);
    o.w = f2bf(tile[c4 + 3][w]);
    *(short4*)(dst + (size_t)w * 64 + c4) = o;
  }
}

// asm helpers: forced global loads + counted waits with register ties so the
// blend data-depends on the wait (closes the rule-18 hoist hazard via
// dataflow). Volatile asm blocks are mutually ordered -> issue order holds.
#define GL16(d, p) \
  asm volatile("global_load_dwordx4 %0, %1, off" : "=v"(d) : "v"(p))
#define WAITV4(a, b, c, d) \
  asm volatile("s_waitcnt vmcnt(4)" : "+v"(a), "+v"(b), "+v"(c), "+v"(d))
#define WAITV0(a, b, c, d) \
  asm volatile("s_waitcnt vmcnt(0)" : "+v"(a), "+v"(b), "+v"(c), "+v"(d))

// ---------------------------------------------------------------------------
// R10 k_omdef: R9 structure + FORCED software pipeline in phase 2.
// Evidence: per-wave accounting closes (36 dependent gather chains x ~900cyc
// ~= the 58% stall); compiler provably sinks source-level prefetch (VGPR
// 52-68 across R3/R4/R9). Fix: inline-asm global_load_dwordx4 one tap ahead
// + counted s_waitcnt vmcnt(4) (T4), params computed two taps ahead so som
// latency overlaps too. All slot indices compile-time (full unroll).
// ---------------------------------------------------------------------------
__global__ __launch_bounds__(512, 4) void k_omdef(
    const short* __restrict__ xT, const short* __restrict__ wt,
    const float* __restrict__ b_om, const float* __restrict__ b_dc,
    short* __restrict__ actT) {
  __shared__ __attribute__((aligned(16))) short lw[18432];  // 36.9KB A-stage
  __shared__ float som[2][27 * 132];                        // 28.5KB

  const int bid = blockIdx.x;
  const int b = bid & 7;
  const int h0 = (bid >> 3) * 2;
  const int tid = threadIdx.x;
  const int wave = tid >> 6, lane = tid & 63, quad = lane >> 4, lr = lane & 15;
  const short* xb = xT + (size_t)b * HWn * 64;
  const int pxl = wave * 16 + lr;

  floatx4 zf = {0.f, 0.f, 0.f, 0.f};
  const short8 zz = (short8){0, 0, 0, 0, 0, 0, 0, 0};

  // ---- stage om A-fragments (both cc halves) ----
  {
    const short8* src = (const short8*)(wt + WOM_OFF);
    short8* dst = (short8*)lw;
    for (int i = tid; i < 2304; i += 512) dst[i] = src[i];
  }
  __syncthreads();

  // ========== phase 1: conv_om (M=32), A shared across both rows ==========
  floatx4 aco[2][2] = {{zf, zf}, {zf, zf}};
#pragma unroll 3
  for (int kk = 0; kk < 9; ++kk) {
    int ky = kk / 3, kx = kk - ky * 3;
    int gx = pxl + kx - 1;
    bool okx = ((unsigned)gx < (unsigned)Wn);
    int gxc = min(max(gx, 0), Wn - 1);
#pragma unroll
    for (int cc = 0; cc < 2; ++cc) {
      short8 a0 = *(const short8*)&lw[((cc * 9 + kk) * 2 + 0) * 512 + lane * 8];
      short8 a1 = *(const short8*)&lw[((cc * 9 + kk) * 2 + 1) * 512 + lane * 8];
#pragma unroll
      for (int r = 0; r < 2; ++r) {
        int gy = h0 + r + ky - 1;
        bool ok = okx && ((unsigned)gy < (unsigned)Hn);
        int gyc = min(max(gy, 0), Hn - 1);
        short8 bf = *(const short8*)(xb + (size_t)(gyc * Wn + gxc) * 64 +
                                     cc * 32 + quad * 8);
        if (!ok) bf = zz;
        aco[r][0] = __builtin_amdgcn_mfma_f32_16x16x32_bf16(a0, bf, aco[r][0], 0, 0, 0);
        aco[r][1] = __builtin_amdgcn_mfma_f32_16x16x32_bf16(a1, bf, aco[r][1], 0, 0, 0);
      }
    }
  }
  // om epilogue -> som (wave-local columns)
#pragma unroll
  for (int r = 0; r < 2; ++r) {
#pragma unroll
    for (int mt = 0; mt < 2; ++mt) {
#pragma unroll
      for (int rr = 0; rr < 4; ++rr) {
        int co = mt * 16 + quad * 4 + rr;
        if (co < 27) {
          float v = aco[r][mt][rr] + b_om[co];
          if (co >= 18) v = 2.f / (1.f + expf(-v));
          som[r][co * 132 + pxl] = v;
        }
      }
    }
  }
  asm volatile("s_waitcnt lgkmcnt(0)" ::: "memory");

  // ========== phase 2: deformable conv (M=64), forced pipeline =============
  floatx4 acc[2][4] = {{zf, zf, zf, zf}, {zf, zf, zf, zf}};
  for (int cc = 0; cc < 2; ++cc) {
    __syncthreads();  // previous lw reads done
    {
      const short8* src = (const short8*)(wt + WDC_OFF + cc * 18432);
      short8* dst = (short8*)lw;
      for (int i = tid; i < 2304; i += 512) dst[i] = src[i];
    }
    __syncthreads();
    const int co = cc * 32 + quad * 8;

    // pipeline state: 2 slots. t = (kk<<1)|r, t in [0,18)
    unsigned pd[2][4];   // gather record indices
    float pu[2][4];      // bilinear weights (param stage)
    short8 q[2][4];      // in-flight gather data
    float us[2][4];      // weights aligned with q

#define PARAM(TT, S)                                                         \
  {                                                                          \
    const int kk_ = (TT) >> 1, r_ = (TT) & 1;                                \
    float offy = som[r_][(2 * kk_) * 132 + pxl];                             \
    float offx = som[r_][(2 * kk_ + 1) * 132 + pxl];                         \
    float m = som[r_][(18 + kk_) * 132 + pxl];                               \
    float py = (float)(h0 + r_ - 1 + (kk_ / 3)) + offy;                      \
    float px_ = (float)(pxl - 1 + (kk_ % 3)) + offx;                         \
    float fy = floorf(py), fx = floorf(px_);                                 \
    float ly = py - fy, lx = px_ - fx;                                       \
    int iy0 = (int)fy, ix0 = (int)fx;                                        \
    int iy1 = iy0 + 1, ix1 = ix0 + 1;                                        \
    bool vy0 = ((unsigned)iy0 < (unsigned)Hn);                               \
    bool vy1 = ((unsigned)iy1 < (unsigned)Hn);                               \
    bool vx0 = ((unsigned)ix0 < (unsigned)Wn);                               \
    bool vx1 = ((unsigned)ix1 < (unsigned)Wn);                               \
    unsigned cy0 = (unsigned)min(max(iy0, 0), Hn - 1);                       \
    unsigned cy1 = (unsigned)min(max(iy1, 0), Hn - 1);                       \
    unsigned cx0 = (unsigned)min(max(ix0, 0), Wn - 1);                       \
    unsigned cx1 = (unsigned)min(max(ix1, 0), Wn - 1);                       \
    pd[S][0] = cy0 * Wn + cx0;                                               \
    pd[S][1] = cy0 * Wn + cx1;                                               \
    pd[S][2] = cy1 * Wn + cx0;                                               \
    pd[S][3] = cy1 * Wn + cx1;                                               \
    pu[S][0] = (vy0 && vx0) ? (1.f - ly) * (1.f - lx) * m : 0.f;             \
    pu[S][1] = (vy0 && vx1) ? (1.f - ly) * lx * m : 0.f;                     \
    pu[S][2] = (vy1 && vx0) ? ly * (1.f - lx) * m : 0.f;                     \
    pu[S][3] = (vy1 && vx1) ? ly * lx * m : 0.f;                             \
  }

#define ISSUE(S)                                                             \
  {                                                                          \
    const short* p0 = xb + (size_t)pd[S][0] * 64 + co;                       \
    const short* p1 = xb + (size_t)pd[S][1] * 64 + co;                       \
    const short* p2 = xb + (size_t)pd[S][2] * 64 + co;                       \
    const short* p3 = xb + (size_t)pd[S][3] * 64 + co;                       \
    GL16(q[S][0], p0);                                                       \
    GL16(q[S][1], p1);                                                       \
    GL16(q[S][2], p2);                                                       \
    GL16(q[S][3], p3);                                                       \
    us[S][0] = pu[S][0]; us[S][1] = pu[S][1];                                \
    us[S][2] = pu[S][2]; us[S][3] = pu[S][3];                                \
  }

    PARAM(0, 0);
    PARAM(1, 1);
    ISSUE(0);  // 4 outstanding
    short8 am0, am1, am2, am3;
#pragma unroll
    for (int t = 0; t < 18; ++t) {
      const int s = t & 1;
      if (t < 17) ISSUE((t + 1) & 1);  // +4 -> 8 outstanding
      if (t < 16) PARAM(t + 2, s);     // som latency overlaps load flight
      if (t < 17) {
        WAITV4(q[s][0], q[s][1], q[s][2], q[s][3]);  // tap t landed
      } else {
        WAITV0(q[s][0], q[s][1], q[s][2], q[s][3]);
      }
      const int kk = t >> 1, r = t & 1;
      if (r == 0) {  // A-frags shared by both rows of this kk
        am0 = *(const short8*)&lw[(kk * 4 + 0) * 512 + lane * 8];
        am1 = *(const short8*)&lw[(kk * 4 + 1) * 512 + lane * 8];
        am2 = *(const short8*)&lw[(kk * 4 + 2) * 512 + lane * 8];
        am3 = *(const short8*)&lw[(kk * 4 + 3) * 512 + lane * 8];
      }
      short8 bf;
#pragma unroll
      for (int e = 0; e < 8; ++e) {
        float f = us[s][0] * bf2f(q[s][0][e]) + us[s][1] * bf2f(q[s][1][e]) +
                  us[s][2] * bf2f(q[s][2][e]) + us[s][3] * bf2f(q[s][3][e]);
        bf[e] = f2bf(f);
      }
      acc[r][0] = __builtin_amdgcn_mfma_f32_16x16x32_bf16(am0, bf, acc[r][0], 0, 0, 0);
      acc[r][1] = __builtin_amdgcn_mfma_f32_16x16x32_bf16(am1, bf, acc[r][1], 0, 0, 0);
      acc[r][2] = __builtin_amdgcn_mfma_f32_16x16x32_bf16(am2, bf, acc[r][2], 0, 0, 0);
      acc[r][3] = __builtin_amdgcn_mfma_f32_16x16x32_bf16(am3, bf, acc[r][3], 0, 0, 0);
    }
#undef PARAM
#undef ISSUE
  }

  // epilogue: bias + leaky ReLU -> actT, both rows
#pragma unroll
  for (int r = 0; r < 2; ++r) {
    short* ab = actT + ((size_t)(b * Hn + h0 + r) * Wn) * 64;
#pragma unroll
    for (int mt = 0; mt < 4; ++mt) {
      int c0 = mt * 16 + quad * 4;
      short4 o;
      float v;
      v = acc[r][mt][0] + b_dc[c0 + 0]; o.x = f2bf(v > 0.f ? v : 0.2f * v);
      v = acc[r][mt][1] + b_dc[c0 + 1]; o.y = f2bf(v > 0.f ? v : 0.2f * v);
      v = acc[r][mt][2] + b_dc[c0 + 2]; o.z = f2bf(v > 0.f ? v : 0.2f * v);
      v = acc[r][mt][3] + b_dc[c0 + 3]; o.w = f2bf(v > 0.f ? v : 0.2f * v);
      *(short4*)(ab + (size_t)pxl * 64 + c0) = o;
    }
  }
}

// ---------------------------------------------------------------------------
// k_conv_out: EXACT R9 version (control). 2 rows/block, A staged per cc and
// shared across rows, B direct shifted global reads, per-row LDS transpose.
// ---------------------------------------------------------------------------
__global__ __launch_bounds__(512, 4) void k_conv_out(
    const short* __restrict__ actT, const short* __restrict__ wt,
    const float* __restrict__ b_c, const float* __restrict__ x,
    float* __restrict__ out) {
  __shared__ __attribute__((aligned(16))) short lw[18432];  // 36.9KB

  const int bid = blockIdx.x;
  const int b = bid & 7;
  const int h0 = (bid >> 3) * 2;
  const int tid = threadIdx.x;
  const int wave = tid >> 6, lane = tid & 63, quad = lane >> 4, lr = lane & 15;
  const short* ab = actT + (size_t)b * HWn * 64;
  const int pxl = wave * 16 + lr;

  floatx4 zf = {0.f, 0.f, 0.f, 0.f};
  const short8 zz = (short8){0, 0, 0, 0, 0, 0, 0, 0};
  floatx4 acc[2][4] = {{zf, zf, zf, zf}, {zf, zf, zf, zf}};

  for (int cc = 0; cc < 2; ++cc) {
    if (cc) __syncthreads();  // previous A-reads done
    {
      const short8* src = (const short8*)(wt + WC_OFF + cc * 18432);
      short8* dst = (short8*)lw;
      for (int i = tid; i < 2304; i += 512) dst[i] = src[i];
    }
    __syncthreads();
    const int co = cc * 32 + quad * 8;
#pragma unroll 3
    for (int kk = 0; kk < 9; ++kk) {
      int ky = kk / 3, kx = kk - ky * 3;
      int gx = pxl + kx - 1;
      bool okx = ((unsigned)gx < (unsigned)Wn);
      int gxc = min(max(gx, 0), Wn - 1);
      short8 am0 = *(const short8*)&lw[(kk * 4 + 0) * 512 + lane * 8];
      short8 am1 = *(const short8*)&lw[(kk * 4 + 1) * 512 + lane * 8];
      short8 am2 = *(const short8*)&lw[(kk * 4 + 2) * 512 + lane * 8];
      short8 am3 = *(const short8*)&lw[(kk * 4 + 3) * 512 + lane * 8];
#pragma unroll
      for (int r = 0; r < 2; ++r) {
        int gy = h0 + r + ky - 1;
        bool ok = okx && ((unsigned)gy < (unsigned)Hn);
        int gyc = min(max(gy, 0), Hn - 1);
        short8 bf = *(const short8*)(ab + (size_t)(gyc * Wn + gxc) * 64 + co);
        if (!ok) bf = zz;
        acc[r][0] = __builtin_amdgcn_mfma_f32_16x16x32_bf16(am0, bf, acc[r][0], 0, 0, 0);
        acc[r][1] = __builtin_amdgcn_mfma_f32_16x16x32_bf16(am1, bf, acc[r][1], 0, 0, 0);
        acc[r][2] = __builtin_amdgcn_mfma_f32_16x16x32_bf16(am2, bf, acc[r][2], 0, 0, 0);
        acc[r][3] = __builtin_amdgcn_mfma_f32_16x16x32_bf16(am3, bf, acc[r][3], 0, 0, 0);
      }
    }
  }
  __syncthreads();  // all A-reads done; reuse lw as fp32 tile

  // per-row epilogue: transpose -> coalesced float4 stores + residual
  float* ot = (float*)lw;
#pragma unroll
  for (int r = 0; r < 2; ++r) {
    if (r) __syncthreads();  // previous row's reads done
#pragma unroll
    for (int mt = 0; mt < 4; ++mt) {
#pragma unroll
      for (int rr = 0; rr < 4; ++rr) {
        ot[(mt * 16 + quad * 4 + rr) * 132 + pxl] = acc[r][mt][rr];
      }
    }
    __syncthreads();
    const int row = tid >> 3, seg = tid & 7;
    const float bias = b_c[row];
    const size_t gbase =
        ((size_t)(b * 64 + row) * Hn + h0 + r) * Wn + seg * 16;
    const float* xr = x + gbase;
    float* op = out + gbase;
#pragma unroll
    for (int j = 0; j < 4; ++j) {
      floatx4 t = *(const floatx4*)&ot[row * 132 + seg * 16 + j * 4];
      floatx4 xv = *(const floatx4*)&xr[j * 4];
      t = t + xv;
      t[0] += bias; t[1] += bias; t[2] += bias; t[3] += bias;
      *(floatx4*)&op[j * 4] = t;
    }
  }
}

// ---------------------------------------------------------------------------
extern "C" void kernel_launch(void* const* d_in, const int* in_sizes, int n_in,
                              void* d_out, int out_size, void* d_ws,
                              size_t ws_size, hipStream_t stream) {
  const float* x = (const float*)d_in[0];
  const float* w_om = (const float*)d_in[1];
  const float* b_om = (const float*)d_in[2];
  const float* w_dc = (const float*)d_in[3];
  const float* b_dc = (const float*)d_in[4];
  const float* w_c = (const float*)d_in[5];
  const float* b_c = (const float*)d_in[6];
  float* out = (float*)d_out;

  // ws: xT bf16 (16.8 MB) | actT bf16 (16.8 MB) | weight frags (184 KB)
  short* xT = (short*)d_ws;
  short* actT = xT + (size_t)Bn * HWn * 64;
  short* wt = actT + (size_t)Bn * HWn * 64;

  k_prep_w<<<dim3(360), 256, 0, stream>>>(w_om, w_dc, w_c, wt);
  k_prep_x<<<dim3(1024), 256, 0, stream>>>(x, xT);
  k_omdef<<<dim3(512), 512, 0, stream>>>(xT, wt, b_om, b_dc, actT);
  k_conv_out<<<dim3(512), 512, 0, stream>>>(actT, wt, b_c, x, out);
}

// Round 11
// 218.236 us; speedup vs baseline: 1.0376x; 1.0376x over previous
//
#include <hip/hip_runtime.h>
#include <math.h>

#define Bn 8
#define Cn 64
#define Hn 128
#define Wn 128
#define HWn (Hn * Wn)

// weight fragment regions (shorts)
#define WOM_OFF 0
#define WDC_OFF 18432
#define WC_OFF 55296

typedef __attribute__((ext_vector_type(8))) short short8;
typedef __attribute__((ext_vector_type(4))) float floatx4;

__device__ __forceinline__ float bf2f(short s) {
  return __uint_as_float(((unsigned)(unsigned short)s) << 16);
}
__device__ __forceinline__ short f2bf(float f) {
  unsigned u = __float_as_uint(f);
  u += 0x7fff + ((u >> 16) & 1);  // RNE
  return (short)(u >> 16);
}

// ---------------------------------------------------------------------------
// Prep 1: weights -> bf16 MFMA-A-fragment order.
// ---------------------------------------------------------------------------
__global__ __launch_bounds__(256) void k_prep_w(
    const float* __restrict__ w_om, const float* __restrict__ w_dc,
    const float* __restrict__ w_c, short* __restrict__ wt) {
  int idx = blockIdx.x * 256 + threadIdx.x;
  if (idx >= 92160) return;
  float v;
  if (idx < WDC_OFF) {  // om region, MT=2 (M=32)
    int e = idx;
    int elem = e & 7, lane = (e >> 3) & 63, mt = (e >> 9) & 1, t = e >> 10;
    int kk = t % 9, cc = t / 9;
    int row = mt * 16 + (lane & 15);
    int cin = cc * 32 + (lane >> 4) * 8 + elem;
    v = (row < 27) ? w_om[(row * 64 + cin) * 9 + kk] : 0.f;
  } else {  // dc / c regions, MT=4 (M=64)
    int e = (idx < WC_OFF) ? idx - WDC_OFF : idx - WC_OFF;
    const float* src = (idx < WC_OFF) ? w_dc : w_c;
    int elem = e & 7, lane = (e >> 3) & 63, mt = (e >> 9) & 3, t = e >> 11;
    int kk = t % 9, cc = t / 9;
    int row = mt * 16 + (lane & 15);
    int cin = cc * 32 + (lane >> 4) * 8 + elem;
    v = src[(row * 64 + cin) * 9 + kk];
  }
  wt[idx] = f2bf(v);
}

// ---------------------------------------------------------------------------
// Prep 2: x fp32 NCHW -> bf16 channels-last xT[b][h][w][64].
// ---------------------------------------------------------------------------
__global__ __launch_bounds__(256) void k_prep_x(const float* __restrict__ x,
                                                short* __restrict__ xT) {
  __shared__ float tile[64][129];
  const int bid = blockIdx.x;
  const int b = bid & 7, h = bid >> 3;
  const int tid = threadIdx.x;
  const float* xb = x + (size_t)b * 64 * HWn + h * Wn;
  for (int i = tid; i < 8192; i += 256) {
    int c = i >> 7, w = i & 127;
    tile[c][w] = xb[c * HWn + w];
  }
  __syncthreads();
  short* dst = xT + ((size_t)(b * Hn + h) * Wn) * 64;
  for (int i = tid; i < 2048; i += 256) {
    int w = i >> 4, c4 = (i & 15) * 4;
    short4 o;
    o.x = f2bf(tile[c4 + 0][w]);
    o.y = f2bf(tile[c4 + 1][w]);
    o.z = f2bf(tile[c4 + 2][w]);
    o.w = f2bf(tile[c4 + 3][w]);
    *(short4*)(dst + (size_t)w * 64 + c4) = o;
  }
}

// ---------------------------------------------------------------------------
// FINAL k_omdef (= R9, best measured 96.2us): 2 output rows per block, grid
// 512 = 2 blocks/CU = one dispatch round. Proven levers: per-block
// amortization (R4), A staged in LDS (R7/R8: removing costs +15us), A-frags
// read once per (cc,kk) and shared by both rows, inline wave-local params
// (som columns are wave-private by the MFMA C/D layout). Residual ~58% stall
// is the dependent gather chain (som->addr->4 scattered L2/HBM loads->blend
// ->MFMA x36); hiding it needs in-flight state whose VGPR cost collapses
// occupancy (R1/R10 both spilled) — structural floor for this decomposition.
// ---------------------------------------------------------------------------
__global__ __launch_bounds__(512, 4) void k_omdef(
    const short* __restrict__ xT, const short* __restrict__ wt,
    const float* __restrict__ b_om, const float* __restrict__ b_dc,
    short* __restrict__ actT) {
  __shared__ __attribute__((aligned(16))) short lw[18432];  // 36.9KB A-stage
  __shared__ float som[2][27 * 132];                        // 28.5KB

  const int bid = blockIdx.x;
  const int b = bid & 7;
  const int h0 = (bid >> 3) * 2;  // first of the two output rows
  const int tid = threadIdx.x;
  const int wave = tid >> 6, lane = tid & 63, quad = lane >> 4, lr = lane & 15;
  const short* xb = xT + (size_t)b * HWn * 64;
  const int pxl = wave * 16 + lr;

  floatx4 zf = {0.f, 0.f, 0.f, 0.f};
  const short8 zz = (short8){0, 0, 0, 0, 0, 0, 0, 0};

  // ---- stage om A-fragments (both cc halves, 36.9KB) ----
  {
    const short8* src = (const short8*)(wt + WOM_OFF);
    short8* dst = (short8*)lw;
    for (int i = tid; i < 2304; i += 512) dst[i] = src[i];
  }
  __syncthreads();

  // ========== phase 1: conv_om (M=32), A shared across both rows ==========
  floatx4 aco[2][2] = {{zf, zf}, {zf, zf}};
#pragma unroll 3
  for (int kk = 0; kk < 9; ++kk) {
    int ky = kk / 3, kx = kk - ky * 3;
    int gx = pxl + kx - 1;
    bool okx = ((unsigned)gx < (unsigned)Wn);
    int gxc = min(max(gx, 0), Wn - 1);
#pragma unroll
    for (int cc = 0; cc < 2; ++cc) {
      short8 a0 = *(const short8*)&lw[((cc * 9 + kk) * 2 + 0) * 512 + lane * 8];
      short8 a1 = *(const short8*)&lw[((cc * 9 + kk) * 2 + 1) * 512 + lane * 8];
#pragma unroll
      for (int r = 0; r < 2; ++r) {
        int gy = h0 + r + ky - 1;
        bool ok = okx && ((unsigned)gy < (unsigned)Hn);
        int gyc = min(max(gy, 0), Hn - 1);
        short8 bf = *(const short8*)(xb + (size_t)(gyc * Wn + gxc) * 64 +
                                     cc * 32 + quad * 8);
        if (!ok) bf = zz;
        aco[r][0] = __builtin_amdgcn_mfma_f32_16x16x32_bf16(a0, bf, aco[r][0], 0, 0, 0);
        aco[r][1] = __builtin_amdgcn_mfma_f32_16x16x32_bf16(a1, bf, aco[r][1], 0, 0, 0);
      }
    }
  }
  // om epilogue -> som (wave-local columns)
#pragma unroll
  for (int r = 0; r < 2; ++r) {
#pragma unroll
    for (int mt = 0; mt < 2; ++mt) {
#pragma unroll
      for (int rr = 0; rr < 4; ++rr) {
        int co = mt * 16 + quad * 4 + rr;
        if (co < 27) {
          float v = aco[r][mt][rr] + b_om[co];
          if (co >= 18) v = 2.f / (1.f + expf(-v));
          som[r][co * 132 + pxl] = v;
        }
      }
    }
  }
  asm volatile("s_waitcnt lgkmcnt(0)" ::: "memory");

  // ========== phase 2: deformable conv (M=64), A shared across rows =======
  floatx4 acc[2][4] = {{zf, zf, zf, zf}, {zf, zf, zf, zf}};
  for (int cc = 0; cc < 2; ++cc) {
    // stage this cc's dc A-half (36.9KB)
    __syncthreads();  // previous lw reads done
    {
      const short8* src = (const short8*)(wt + WDC_OFF + cc * 18432);
      short8* dst = (short8*)lw;
      for (int i = tid; i < 2304; i += 512) dst[i] = src[i];
    }
    __syncthreads();
    const int co = cc * 32 + quad * 8;
#pragma unroll 3
    for (int kk = 0; kk < 9; ++kk) {
      short8 am0 = *(const short8*)&lw[(kk * 4 + 0) * 512 + lane * 8];
      short8 am1 = *(const short8*)&lw[(kk * 4 + 1) * 512 + lane * 8];
      short8 am2 = *(const short8*)&lw[(kk * 4 + 2) * 512 + lane * 8];
      short8 am3 = *(const short8*)&lw[(kk * 4 + 3) * 512 + lane * 8];
#pragma unroll
      for (int r = 0; r < 2; ++r) {
        // inline bilinear params (wave-local som)
        float offy = som[r][(2 * kk) * 132 + pxl];
        float offx = som[r][(2 * kk + 1) * 132 + pxl];
        float m = som[r][(18 + kk) * 132 + pxl];
        float py = (float)(h0 + r - 1 + (kk / 3)) + offy;
        float px_ = (float)(pxl - 1 + (kk % 3)) + offx;
        float fy = floorf(py), fx = floorf(px_);
        float ly = py - fy, lx = px_ - fx;
        int iy0 = (int)fy, ix0 = (int)fx;
        int iy1 = iy0 + 1, ix1 = ix0 + 1;
        bool vy0 = ((unsigned)iy0 < (unsigned)Hn);
        bool vy1 = ((unsigned)iy1 < (unsigned)Hn);
        bool vx0 = ((unsigned)ix0 < (unsigned)Wn);
        bool vx1 = ((unsigned)ix1 < (unsigned)Wn);
        unsigned cy0 = (unsigned)min(max(iy0, 0), Hn - 1);
        unsigned cy1 = (unsigned)min(max(iy1, 0), Hn - 1);
        unsigned cx0 = (unsigned)min(max(ix0, 0), Wn - 1);
        unsigned cx1 = (unsigned)min(max(ix1, 0), Wn - 1);
        unsigned d0 = cy0 * Wn + cx0, d1 = cy0 * Wn + cx1;
        unsigned d2 = cy1 * Wn + cx0, d3 = cy1 * Wn + cx1;
        float u0 = (vy0 && vx0) ? (1.f - ly) * (1.f - lx) * m : 0.f;
        float u1 = (vy0 && vx1) ? (1.f - ly) * lx * m : 0.f;
        float u2 = (vy1 && vx0) ? ly * (1.f - lx) * m : 0.f;
        float u3 = (vy1 && vx1) ? ly * lx * m : 0.f;

        short8 q0 = *(const short8*)(xb + (size_t)d0 * 64 + co);
        short8 q1 = *(const short8*)(xb + (size_t)d1 * 64 + co);
        short8 q2 = *(const short8*)(xb + (size_t)d2 * 64 + co);
        short8 q3 = *(const short8*)(xb + (size_t)d3 * 64 + co);

        short8 bf;
#pragma unroll
        for (int e = 0; e < 8; ++e) {
          float f = u0 * bf2f(q0[e]) + u1 * bf2f(q1[e]) + u2 * bf2f(q2[e]) +
                    u3 * bf2f(q3[e]);
          bf[e] = f2bf(f);
        }
        acc[r][0] = __builtin_amdgcn_mfma_f32_16x16x32_bf16(am0, bf, acc[r][0], 0, 0, 0);
        acc[r][1] = __builtin_amdgcn_mfma_f32_16x16x32_bf16(am1, bf, acc[r][1], 0, 0, 0);
        acc[r][2] = __builtin_amdgcn_mfma_f32_16x16x32_bf16(am2, bf, acc[r][2], 0, 0, 0);
        acc[r][3] = __builtin_amdgcn_mfma_f32_16x16x32_bf16(am3, bf, acc[r][3], 0, 0, 0);
      }
    }
  }

  // epilogue: bias + leaky ReLU -> actT, both rows
#pragma unroll
  for (int r = 0; r < 2; ++r) {
    short* ab = actT + ((size_t)(b * Hn + h0 + r) * Wn) * 64;
#pragma unroll
    for (int mt = 0; mt < 4; ++mt) {
      int c0 = mt * 16 + quad * 4;
      short4 o;
      float v;
      v = acc[r][mt][0] + b_dc[c0 + 0]; o.x = f2bf(v > 0.f ? v : 0.2f * v);
      v = acc[r][mt][1] + b_dc[c0 + 1]; o.y = f2bf(v > 0.f ? v : 0.2f * v);
      v = acc[r][mt][2] + b_dc[c0 + 2]; o.z = f2bf(v > 0.f ? v : 0.2f * v);
      v = acc[r][mt][3] + b_dc[c0 + 3]; o.w = f2bf(v > 0.f ? v : 0.2f * v);
      *(short4*)(ab + (size_t)pxl * 64 + c0) = o;
    }
  }
}

// ---------------------------------------------------------------------------
// FINAL k_conv_out (= R9): 2 rows per block, grid 512 = one round. A staged
// per cc in LDS, read once per (cc,kk) and shared by both rows; B = direct
// shifted global reads. Epilogue per row via LDS fp32 transpose.
// ---------------------------------------------------------------------------
__global__ __launch_bounds__(512, 4) void k_conv_out(
    const short* __restrict__ actT, const short* __restrict__ wt,
    const float* __restrict__ b_c, const float* __restrict__ x,
    float* __restrict__ out) {
  __shared__ __attribute__((aligned(16))) short lw[18432];  // 36.9KB

  const int bid = blockIdx.x;
  const int b = bid & 7;
  const int h0 = (bid >> 3) * 2;
  const int tid = threadIdx.x;
  const int wave = tid >> 6, lane = tid & 63, quad = lane >> 4, lr = lane & 15;
  const short* ab = actT + (size_t)b * HWn * 64;
  const int pxl = wave * 16 + lr;

  floatx4 zf = {0.f, 0.f, 0.f, 0.f};
  const short8 zz = (short8){0, 0, 0, 0, 0, 0, 0, 0};
  floatx4 acc[2][4] = {{zf, zf, zf, zf}, {zf, zf, zf, zf}};

  for (int cc = 0; cc < 2; ++cc) {
    if (cc) __syncthreads();  // previous A-reads done
    {
      const short8* src = (const short8*)(wt + WC_OFF + cc * 18432);
      short8* dst = (short8*)lw;
      for (int i = tid; i < 2304; i += 512) dst[i] = src[i];
    }
    __syncthreads();
    const int co = cc * 32 + quad * 8;
#pragma unroll 3
    for (int kk = 0; kk < 9; ++kk) {
      int ky = kk / 3, kx = kk - ky * 3;
      int gx = pxl + kx - 1;
      bool okx = ((unsigned)gx < (unsigned)Wn);
      int gxc = min(max(gx, 0), Wn - 1);
      short8 am0 = *(const short8*)&lw[(kk * 4 + 0) * 512 + lane * 8];
      short8 am1 = *(const short8*)&lw[(kk * 4 + 1) * 512 + lane * 8];
      short8 am2 = *(const short8*)&lw[(kk * 4 + 2) * 512 + lane * 8];
      short8 am3 = *(const short8*)&lw[(kk * 4 + 3) * 512 + lane * 8];
#pragma unroll
      for (int r = 0; r < 2; ++r) {
        int gy = h0 + r + ky - 1;
        bool ok = okx && ((unsigned)gy < (unsigned)Hn);
        int gyc = min(max(gy, 0), Hn - 1);
        short8 bf = *(const short8*)(ab + (size_t)(gyc * Wn + gxc) * 64 + co);
        if (!ok) bf = zz;
        acc[r][0] = __builtin_amdgcn_mfma_f32_16x16x32_bf16(am0, bf, acc[r][0], 0, 0, 0);
        acc[r][1] = __builtin_amdgcn_mfma_f32_16x16x32_bf16(am1, bf, acc[r][1], 0, 0, 0);
        acc[r][2] = __builtin_amdgcn_mfma_f32_16x16x32_bf16(am2, bf, acc[r][2], 0, 0, 0);
        acc[r][3] = __builtin_amdgcn_mfma_f32_16x16x32_bf16(am3, bf, acc[r][3], 0, 0, 0);
      }
    }
  }
  __syncthreads();  // all A-reads done; reuse lw as fp32 tile

  // per-row epilogue: transpose -> coalesced float4 stores + residual
  float* ot = (float*)lw;
#pragma unroll
  for (int r = 0; r < 2; ++r) {
    if (r) __syncthreads();  // previous row's reads done
#pragma unroll
    for (int mt = 0; mt < 4; ++mt) {
#pragma unroll
      for (int rr = 0; rr < 4; ++rr) {
        ot[(mt * 16 + quad * 4 + rr) * 132 + pxl] = acc[r][mt][rr];
      }
    }
    __syncthreads();
    const int row = tid >> 3, seg = tid & 7;
    const float bias = b_c[row];
    const size_t gbase =
        ((size_t)(b * 64 + row) * Hn + h0 + r) * Wn + seg * 16;
    const float* xr = x + gbase;
    float* op = out + gbase;
#pragma unroll
    for (int j = 0; j < 4; ++j) {
      floatx4 t = *(const floatx4*)&ot[row * 132 + seg * 16 + j * 4];
      floatx4 xv = *(const floatx4*)&xr[j * 4];
      t = t + xv;
      t[0] += bias; t[1] += bias; t[2] += bias; t[3] += bias;
      *(floatx4*)&op[j * 4] = t;
    }
  }
}

// ---------------------------------------------------------------------------
extern "C" void kernel_launch(void* const* d_in, const int* in_sizes, int n_in,
                              void* d_out, int out_size, void* d_ws,
                              size_t ws_size, hipStream_t stream) {
  const float* x = (const float*)d_in[0];
  const float* w_om = (const float*)d_in[1];
  const float* b_om = (const float*)d_in[2];
  const float* w_dc = (const float*)d_in[3];
  const float* b_dc = (const float*)d_in[4];
  const float* w_c = (const float*)d_in[5];
  const float* b_c = (const float*)d_in[6];
  float* out = (float*)d_out;

  // ws: xT bf16 (16.8 MB) | actT bf16 (16.8 MB) | weight frags (184 KB)
  short* xT = (short*)d_ws;
  short* actT = xT + (size_t)Bn * HWn * 64;
  short* wt = actT + (size_t)Bn * HWn * 64;

  k_prep_w<<<dim3(360), 256, 0, stream>>>(w_om, w_dc, w_c, wt);
  k_prep_x<<<dim3(1024), 256, 0, stream>>>(x, xT);
  k_omdef<<<dim3(512), 512, 0, stream>>>(xT, wt, b_om, b_dc, actT);
  k_conv_out<<<dim3(512), 512, 0, stream>>>(actT, wt, b_c, x, out);
}